// Round 9
// baseline (374.481 us; speedup 1.0000x reference)
//
#include <hip/hip_runtime.h>
#include <stdint.h>

#define Bsz 2
#define Sseq 2048
#define Hdim 2048
#define NH 32
#define NKV 8
#define HD 64
#define RANKD 16
#define LSCALE (1.0f/16.0f)
#define Mrows (Bsz*Sseq)      // 4096
#define NQKV 3072             // 2048 q + 512 k + 512 v

typedef unsigned short u16;
typedef __bf16 bf16x8 __attribute__((ext_vector_type(8)));
typedef float f32x4 __attribute__((ext_vector_type(4)));
typedef float f32x16 __attribute__((ext_vector_type(16)));

#define MFMA32(A, B, C) __builtin_amdgcn_mfma_f32_32x32x16_bf16(A, B, C, 0, 0, 0)

__device__ __forceinline__ u16 f2bf(float f) {
  union { float f; uint32_t u; } v; v.f = f;
  uint32_t u = v.u;
  return (u16)((u + 0x7fffu + ((u >> 16) & 1u)) >> 16);   // round-nearest-even
}
__device__ __forceinline__ float bf2f(u16 b) {
  union { uint32_t u; float f; } v; v.u = ((uint32_t)b) << 16;
  return v.f;
}

#define GLD_LDS16(g, l) \
  __builtin_amdgcn_global_load_lds((const __attribute__((address_space(1))) void*)(g), \
                                   (__attribute__((address_space(3))) void*)(l), 16, 0, 0)

// ---------------- f32 -> bf16 convert (x) ----------------
__global__ void cvt_bf16_kernel(const float* __restrict__ in, u16* __restrict__ out, int n4) {
  int i = blockIdx.x * 256 + threadIdx.x;
  if (i >= n4) return;
  float4 v = ((const float4*)in)[i];
  ushort4 o;
  o.x = f2bf(v.x); o.y = f2bf(v.y); o.z = f2bf(v.z); o.w = f2bf(v.w);
  ((ushort4*)out)[i] = o;
}

// ---------------- W_eff = W + SCALE * (A@B)^T  (bf16 out) ----------------
__global__ void weff_kernel(const float* __restrict__ W, const float* __restrict__ A,
                            const float* __restrict__ Bm, u16* __restrict__ out,
                            int N, int K) {
  __shared__ float bcol[RANKD];
  int k = blockIdx.x * 256 + threadIdx.x;
  int n = blockIdx.y;
  if (threadIdx.x < RANKD) bcol[threadIdx.x] = Bm[threadIdx.x * N + n];
  __syncthreads();
  float acc = 0.f;
#pragma unroll
  for (int r = 0; r < RANKD; ++r) acc += A[k * RANKD + r] * bcol[r];
  out[(size_t)n * K + k] = f2bf(W[(size_t)n * K + k] + acc * LSCALE);
}

// ---------------- bf16 GEMM, B-transposed layout (m97 structure) ----------------
template <typename OutT>
__global__ __launch_bounds__(256) void gemm_bt(const u16* __restrict__ A,
                                               const u16* __restrict__ Bw,
                                               OutT* __restrict__ C,
                                               int M, int N, int K) {
  __shared__ u16 As[128 * 64];
  __shared__ u16 Bs[128 * 64];
  const int t = threadIdx.x, lane = t & 63, w = t >> 6;
  const int bm0 = blockIdx.x * 128, bn0 = blockIdx.y * 128;
  const int wm = (w >> 1) * 64, wn = (w & 1) * 64;
  f32x4 acc[4][4] = {};
  for (int kt = 0; kt < K; kt += 64) {
#pragma unroll
    for (int i = 0; i < 4; ++i) {
      int offw = i * 4096 + w * 1024;
      int offl = offw + lane * 16;
      int row = offl >> 7;
      int cb  = offl & 127;
      const u16* ga = A  + (size_t)(bm0 + row) * K + kt + (cb >> 1);
      GLD_LDS16(ga, (char*)As + offw);
      const u16* gb = Bw + (size_t)(bn0 + row) * K + kt + (cb >> 1);
      GLD_LDS16(gb, (char*)Bs + offw);
    }
    __syncthreads();
#pragma unroll
    for (int kk = 0; kk < 2; ++kk) {
      const int col = kk * 32 + (lane >> 4) * 8;
      bf16x8 af[4], bfr[4];
#pragma unroll
      for (int mi = 0; mi < 4; ++mi)
        af[mi] = *(const bf16x8*)&As[(wm + mi * 16 + (lane & 15)) * 64 + col];
#pragma unroll
      for (int ni = 0; ni < 4; ++ni)
        bfr[ni] = *(const bf16x8*)&Bs[(wn + ni * 16 + (lane & 15)) * 64 + col];
#pragma unroll
      for (int mi = 0; mi < 4; ++mi)
#pragma unroll
        for (int ni = 0; ni < 4; ++ni)
          acc[mi][ni] = __builtin_amdgcn_mfma_f32_16x16x32_bf16(af[mi], bfr[ni], acc[mi][ni], 0, 0, 0);
    }
    __syncthreads();
  }
  const int r0 = (lane >> 4) * 4, cq = lane & 15;
#pragma unroll
  for (int mi = 0; mi < 4; ++mi)
#pragma unroll
    for (int ni = 0; ni < 4; ++ni) {
      size_t base = (size_t)(bm0 + wm + mi * 16 + r0) * N + bn0 + wn + ni * 16 + cq;
#pragma unroll
      for (int r = 0; r < 4; ++r) {
        float v = acc[mi][ni][r];
        if constexpr (sizeof(OutT) == 2) C[base + (size_t)r * N] = f2bf(v);
        else                             C[base + (size_t)r * N] = v;
      }
    }
}

// ---------------- RoPE q: qkv bf16 [M,3072] -> qb bf16 [B,NH,S,HD] ----------------
__global__ void rope_q_kernel(const u16* __restrict__ qkv, const int* __restrict__ pid,
                              u16* __restrict__ qb) {
  int idx = blockIdx.x * 256 + threadIdx.x;
  int i = idx & 31;
  int s = (idx >> 5) & (Sseq - 1);
  int h = (idx >> 16) & (NH - 1);
  int b = idx >> 21;
  int row = b * Sseq + s;
  const u16* src = qkv + (size_t)row * NQKV + h * HD + i;
  float q0 = bf2f(src[0]);
  float q1 = bf2f(src[32]);
  float pos = (float)pid[row];
  float ang = pos * expf(-(float)i * (9.210340371976184f / 32.f));
  float c = cosf(ang), sn = sinf(ang);
  u16* dst = qb + ((size_t)(b * NH + h) * Sseq + s) * HD + i;
  dst[0]  = f2bf(q0 * c - q1 * sn);
  dst[32] = f2bf(q1 * c + q0 * sn);
}

// ---------------- RoPE k (pre-scaled by log2(e)/sqrt(HD)): -> kb bf16 [B,NKV,S,HD] --
__global__ void rope_k_kernel(const u16* __restrict__ qkv, const int* __restrict__ pid,
                              u16* __restrict__ kb) {
  const float SCK = 0.18033688011112042f;  // log2(e)/8
  int idx = blockIdx.x * 256 + threadIdx.x;
  int i = idx & 31;
  int s = (idx >> 5) & (Sseq - 1);
  int h = (idx >> 16) & (NKV - 1);
  int b = idx >> 19;
  int row = b * Sseq + s;
  const u16* src = qkv + (size_t)row * NQKV + 2048 + h * HD + i;
  float q0 = bf2f(src[0]);
  float q1 = bf2f(src[32]);
  float pos = (float)pid[row];
  float ang = pos * expf(-(float)i * (9.210340371976184f / 32.f));
  float c = cosf(ang), sn = sinf(ang);
  u16* dst = kb + ((size_t)(b * NKV + h) * Sseq + s) * HD + i;
  dst[0]  = f2bf((q0 * c - q1 * sn) * SCK);
  dst[32] = f2bf((q1 * c + q0 * sn) * SCK);
}

// ---------------- V transpose: qkv bf16 -> vT bf16 [B,NKV,HD,S] ----------------
__global__ void pack_vT_kernel(const u16* __restrict__ qkv, u16* __restrict__ vT) {
  __shared__ u16 tile[64][72];
  int bh = blockIdx.y;
  int s0 = blockIdx.x * 64;
  int b = bh >> 3, hkv = bh & 7;
  int t = threadIdx.x;
#pragma unroll
  for (int ii = 0; ii < 16; ++ii) {
    int lin = ii * 256 + t;
    int sl = lin >> 6, d = lin & 63;
    tile[sl][d] = qkv[(size_t)(b * Sseq + s0 + sl) * NQKV + 2560 + hkv * HD + d];
  }
  __syncthreads();
#pragma unroll
  for (int ii = 0; ii < 16; ++ii) {
    int lin = ii * 256 + t;
    int d = lin >> 6, sl = lin & 63;
    vT[((size_t)bh * HD + d) * Sseq + s0 + sl] = tile[sl][d];
  }
}

// ---------------- flash attention step (round-6-proven body) ----------------
template <bool MASKED>
__device__ __forceinline__ void attn_step(int k0, int qg, int hi, int q,
                                          const u16* __restrict__ kbp,
                                          const u16* __restrict__ vbp,
                                          const bf16x8 (&qf)[4],
                                          f32x16& o0, f32x16& o1,
                                          float& m, float& lsum) {
  bf16x8 kf0[4], kf1[4];
#pragma unroll
  for (int dk = 0; dk < 4; ++dk) {
    const u16* kp = kbp + (size_t)(k0 + q) * HD + dk * 16 + hi * 8;
    kf0[dk] = *(const bf16x8*)kp;
    kf1[dk] = *(const bf16x8*)(kp + 32 * HD);
  }
  f32x16 st0 = {}, st1 = {};
#pragma unroll
  for (int dk = 0; dk < 4; ++dk) {
    st0 = MFMA32(kf0[dk], qf[dk], st0);
    st1 = MFMA32(kf1[dk], qf[dk], st1);
  }
  bf16x8 vf0[4], vf1[4];
#pragma unroll
  for (int ks = 0; ks < 4; ++ks) {
    const u16* vp = vbp + (size_t)q * Sseq + k0 + ks * 16 + hi * 8;
    vf0[ks] = *(const bf16x8*)vp;
    vf1[ks] = *(const bf16x8*)(vp + 32 * Sseq);
  }
  if (MASKED) {
#pragma unroll
    for (int r = 0; r < 16; ++r) {
      const int koff = (r & 3) + 8 * (r >> 2) + 4 * hi;
      if (k0 + koff > qg)      st0[r] = -3.0e38f;
      if (k0 + 32 + koff > qg) st1[r] = -3.0e38f;
    }
  }
  // tree-reduce max (depth 5, ILP); per-half only — cross-half shfl deferred
  float t01[16];
#pragma unroll
  for (int r = 0; r < 16; ++r) t01[r] = fmaxf(st0[r], st1[r]);
#pragma unroll
  for (int s = 8; s > 0; s >>= 1)
#pragma unroll
    for (int r = 0; r < s; ++r) t01[r] = fmaxf(t01[r], t01[r + s]);
  float tmax = t01[0];
  if (__any(tmax > m + 8.f)) {                // defer-max (T13)
    float tx = fmaxf(tmax, __shfl_xor(tmax, 32));
    float mnew = fmaxf(m, tx);
    float al = exp2f(m - mnew);
    lsum *= al;
#pragma unroll
    for (int r = 0; r < 16; ++r) { o0[r] *= al; o1[r] *= al; }
    m = mnew;
  }
  float ps[16];
#pragma unroll
  for (int r = 0; r < 16; ++r) {
    float e0 = exp2f(st0[r] - m), e1 = exp2f(st1[r] - m);
    st0[r] = e0; st1[r] = e1;
    ps[r] = e0 + e1;
  }
#pragma unroll
  for (int s = 8; s > 0; s >>= 1)
#pragma unroll
    for (int r = 0; r < s; ++r) ps[r] += ps[r + s];
  lsum += ps[0];                 // lane-partial; cross-half combine in epilogue
  // P -> bf16 fragments via cvt_pk + permlane32_swap (T12; round-2-proven)
  bf16x8 pa[4];
#pragma unroll
  for (int ks = 0; ks < 4; ++ks) {
    const int sel = (ks & 1) * 8;
    f32x16& stt = (ks < 2) ? st0 : st1;
    uint32_t X0, Y0, X1, Y1;
    asm("v_cvt_pk_bf16_f32 %0, %1, %2" : "=v"(X0) : "v"(stt[sel + 0]), "v"(stt[sel + 1]));
    asm("v_cvt_pk_bf16_f32 %0, %1, %2" : "=v"(Y0) : "v"(stt[sel + 4]), "v"(stt[sel + 5]));
    asm("v_cvt_pk_bf16_f32 %0, %1, %2" : "=v"(X1) : "v"(stt[sel + 2]), "v"(stt[sel + 3]));
    asm("v_cvt_pk_bf16_f32 %0, %1, %2" : "=v"(Y1) : "v"(stt[sel + 6]), "v"(stt[sel + 7]));
    asm volatile("v_permlane32_swap_b32 %0, %1" : "+v"(X0), "+v"(Y0));
    asm volatile("v_permlane32_swap_b32 %0, %1" : "+v"(X1), "+v"(Y1));
    union { uint32_t w[4]; bf16x8 v; } u_;
    u_.w[0] = X0; u_.w[1] = X1; u_.w[2] = Y0; u_.w[3] = Y1;
    pa[ks] = u_.v;
  }
#pragma unroll
  for (int ks = 0; ks < 4; ++ks) {
    o0 = MFMA32(vf0[ks], pa[ks], o0);
    o1 = MFMA32(vf1[ks], pa[ks], o1);
  }
}

// 1024 blocks x 4 waves. Heavy/light pairing WITHIN each block:
// block i: p=i>>5, j=i&31; wave wid -> bh = 2j+(wid>>1), qt = (wid&1)? p : 63-p.
// Every block = 2 heavy + 2 light waves = 67 wave-steps exactly, so per-CU work
// is ~264 wave-steps under ANY placement, while keeping the 16-waves/CU cap
// (rounds 7/8 showed balance OR occupancy alone is not enough — need both).
__global__ __launch_bounds__(256) void attn_kernel(const u16* __restrict__ qb,
                                                   const u16* __restrict__ kb,
                                                   const u16* __restrict__ vT,
                                                   u16* __restrict__ aout) {
  __shared__ uint32_t ldso[4][32 * 33];
  const int tid = threadIdx.x;
  const int lane = tid & 63, wid = tid >> 6;
  const int q = lane & 31, hi = lane >> 5;
  const int blk = blockIdx.x;
  const int p = blk >> 5, j = blk & 31;
  const int bh = 2 * j + (wid >> 1);     // wave-pairs share one KV stream
  const int qt = (wid & 1) ? p : 63 - p; // heavy/light inside the block
  const int b = bh >> 5, h = bh & 31, hkv = h >> 2;
  const int qbase = qt * 32, qg = qbase + q;

  const u16* qp = qb + ((size_t)bh * Sseq + qg) * HD + hi * 8;
  bf16x8 qf[4];
#pragma unroll
  for (int dk = 0; dk < 4; ++dk) qf[dk] = *(const bf16x8*)(qp + dk * 16);

  const u16* kbp = kb + (size_t)(b * NKV + hkv) * Sseq * HD;
  const u16* vbp = vT + (size_t)(b * NKV + hkv) * HD * Sseq;

  f32x16 o0 = {}, o1 = {};
  float m = -INFINITY, lsum = 0.f;
  const int ntiles = (qt >> 1) + 1;

  for (int kt = 0; kt < ntiles - 1; ++kt)
    attn_step<false>(kt * 64, qg, hi, q, kbp, vbp, qf, o0, o1, m, lsum);
  attn_step<true>((ntiles - 1) * 64, qg, hi, q, kbp, vbp, qf, o0, o1, m, lsum);

  lsum += __shfl_xor(lsum, 32);        // cross-half lsum combine
  const float inv = 1.f / lsum;

  // epilogue transpose via packed-bf16 u32 LDS (per-wave slice, in-order DS)
  uint32_t* lw = ldso[wid];
#pragma unroll
  for (int rr = 0; rr < 16; rr += 2) {
    const int d2 = ((rr >> 1) & 1) + 4 * (rr >> 2) + 2 * hi;
    uint32_t w0, w1;
    asm("v_cvt_pk_bf16_f32 %0, %1, %2" : "=v"(w0) : "v"(o0[rr] * inv), "v"(o0[rr + 1] * inv));
    asm("v_cvt_pk_bf16_f32 %0, %1, %2" : "=v"(w1) : "v"(o1[rr] * inv), "v"(o1[rr + 1] * inv));
    lw[d2 * 33 + q]        = w0;
    lw[(16 + d2) * 33 + q] = w1;
  }
  asm volatile("s_waitcnt lgkmcnt(0)" ::: "memory");
  __builtin_amdgcn_sched_barrier(0);
  uint32_t wv[16];
#pragma unroll
  for (int jj = 0; jj < 16; ++jj) wv[jj] = lw[(hi * 16 + jj) * 33 + q];
  uint4* op4 = (uint4*)(aout + (size_t)(b * Sseq + qbase + q) * (NH * HD) + h * HD + hi * 32);
#pragma unroll
  for (int k4 = 0; k4 < 4; ++k4)
    op4[k4] = make_uint4(wv[4 * k4], wv[4 * k4 + 1], wv[4 * k4 + 2], wv[4 * k4 + 3]);
}

extern "C" void kernel_launch(void* const* d_in, const int* in_sizes, int n_in,
                              void* d_out, int out_size, void* d_ws, size_t ws_size,
                              hipStream_t stream) {
  const float* x  = (const float*)d_in[0];
  const int*   pid= (const int*)d_in[1];
  const float* Wq = (const float*)d_in[2];
  const float* Wk = (const float*)d_in[3];
  const float* Wv = (const float*)d_in[4];
  const float* Wo = (const float*)d_in[5];
  const float* Aq = (const float*)d_in[6];
  const float* Bq = (const float*)d_in[7];
  const float* Ak = (const float*)d_in[8];
  const float* Bk = (const float*)d_in[9];
  const float* Av = (const float*)d_in[10];
  const float* Bv = (const float*)d_in[11];
  const float* Ao = (const float*)d_in[12];
  const float* Bo = (const float*)d_in[13];
  float* out = (float*)d_out;

  char* w = (char*)d_ws;
  u16*   x_bf    = (u16*)w;   w += (size_t)Mrows * Hdim * 2;
  u16*   weffqkv = (u16*)w;   w += (size_t)NQKV * Hdim * 2;
  u16*   weffo   = (u16*)w;   w += (size_t)Hdim * Hdim * 2;
  u16*   qkv     = (u16*)w;   w += (size_t)Mrows * NQKV * 2;
  u16*   qbb     = (u16*)w;   w += (size_t)Bsz * NH * Sseq * HD * 2;
  u16*   kbb     = (u16*)w;   w += (size_t)Bsz * NKV * Sseq * HD * 2;
  u16*   vTb     = (u16*)w;   w += (size_t)Bsz * NKV * Sseq * HD * 2;
  u16*   aoutb   = (u16*)w;   w += (size_t)Mrows * (NH * HD) * 2;

  cvt_bf16_kernel<<<8192, 256, 0, stream>>>(x, x_bf, Mrows * Hdim / 4);

  weff_kernel<<<dim3(8, 2048), 256, 0, stream>>>(Wq, Aq, Bq, weffqkv, 2048, 2048);
  weff_kernel<<<dim3(8, 512),  256, 0, stream>>>(Wk, Ak, Bk, weffqkv + (size_t)2048 * 2048, 512, 2048);
  weff_kernel<<<dim3(8, 512),  256, 0, stream>>>(Wv, Av, Bv, weffqkv + (size_t)2560 * 2048, 512, 2048);
  weff_kernel<<<dim3(8, 2048), 256, 0, stream>>>(Wo, Ao, Bo, weffo, 2048, 2048);

  gemm_bt<u16><<<dim3(32, 24), 256, 0, stream>>>(x_bf, weffqkv, qkv, Mrows, NQKV, Hdim);

  rope_q_kernel<<<16384, 256, 0, stream>>>(qkv, pid, qbb);
  rope_k_kernel<<<4096, 256, 0, stream>>>(qkv, pid, kbb);
  pack_vT_kernel<<<dim3(32, 16), 256, 0, stream>>>(qkv, vTb);

  attn_kernel<<<1024, 256, 0, stream>>>(qbb, kbb, vTb, aoutb);

  gemm_bt<float><<<dim3(32, 16), 256, 0, stream>>>(aoutb, weffo, out, Mrows, 2048, 2048);
}

// Round 10
// 332.467 us; speedup vs baseline: 1.1264x; 1.1264x over previous
//
#include <hip/hip_runtime.h>
#include <stdint.h>

#define Bsz 2
#define Sseq 2048
#define Hdim 2048
#define NH 32
#define NKV 8
#define HD 64
#define RANKD 16
#define LSCALE (1.0f/16.0f)
#define Mrows (Bsz*Sseq)      // 4096
#define NQKV 3072             // 2048 q + 512 k + 512 v

typedef unsigned short u16;
typedef __bf16 bf16x8 __attribute__((ext_vector_type(8)));
typedef float f32x4 __attribute__((ext_vector_type(4)));
typedef float f32x16 __attribute__((ext_vector_type(16)));

#define MFMA32(A, B, C) __builtin_amdgcn_mfma_f32_32x32x16_bf16(A, B, C, 0, 0, 0)

__device__ __forceinline__ u16 f2bf(float f) {
  union { float f; uint32_t u; } v; v.f = f;
  uint32_t u = v.u;
  return (u16)((u + 0x7fffu + ((u >> 16) & 1u)) >> 16);   // round-nearest-even
}
__device__ __forceinline__ float bf2f(u16 b) {
  union { uint32_t u; float f; } v; v.u = ((uint32_t)b) << 16;
  return v.f;
}

#define GLD_LDS16(g, l) \
  __builtin_amdgcn_global_load_lds((const __attribute__((address_space(1))) void*)(g), \
                                   (__attribute__((address_space(3))) void*)(l), 16, 0, 0)

// ---------------- prep: 4x W_eff (bf16) + x f32->bf16, fused ----------------
// blocks [0, 40960): weff — y = bid>>3 decodes segment; k = (bid&7)*256 + tid.
// blocks [40960, 49152): cvt — i = (bid-40960)*256 + tid, float4->bf16x4.
__global__ void prep_kernel(const float* __restrict__ x, u16* __restrict__ x_bf,
                            const float* __restrict__ Wq, const float* __restrict__ Aq, const float* __restrict__ Bq,
                            const float* __restrict__ Wk, const float* __restrict__ Ak, const float* __restrict__ Bk,
                            const float* __restrict__ Wv, const float* __restrict__ Av, const float* __restrict__ Bv,
                            const float* __restrict__ Wo, const float* __restrict__ Ao, const float* __restrict__ Bo,
                            u16* __restrict__ weffqkv, u16* __restrict__ weffo) {
  __shared__ float bcol[RANKD];
  const int bid = blockIdx.x, tid = threadIdx.x;
  if (bid < 40960) {
    const int y = bid >> 3;
    const int k = (bid & 7) * 256 + tid;
    const float *W, *A, *Bm;
    u16* out;
    int N, n;
    if (y < 2048)      { W = Wq; A = Aq; Bm = Bq; out = weffqkv;                         N = 2048; n = y; }
    else if (y < 2560) { W = Wk; A = Ak; Bm = Bk; out = weffqkv + (size_t)2048 * Hdim;   N = 512;  n = y - 2048; }
    else if (y < 3072) { W = Wv; A = Av; Bm = Bv; out = weffqkv + (size_t)2560 * Hdim;   N = 512;  n = y - 2560; }
    else               { W = Wo; A = Ao; Bm = Bo; out = weffo;                           N = 2048; n = y - 3072; }
    if (tid < RANKD) bcol[tid] = Bm[tid * N + n];
    __syncthreads();
    float acc = 0.f;
#pragma unroll
    for (int r = 0; r < RANKD; ++r) acc += A[k * RANKD + r] * bcol[r];
    out[(size_t)n * Hdim + k] = f2bf(W[(size_t)n * Hdim + k] + acc * LSCALE);
  } else {
    const int i = (bid - 40960) * 256 + tid;      // i < 2097152 exactly
    float4 v = ((const float4*)x)[i];
    ushort4 o;
    o.x = f2bf(v.x); o.y = f2bf(v.y); o.z = f2bf(v.z); o.w = f2bf(v.w);
    ((ushort4*)x_bf)[i] = o;
  }
}

// ---------------- bf16 GEMM, B-transposed layout (m97 structure) ----------------
template <typename OutT>
__global__ __launch_bounds__(256) void gemm_bt(const u16* __restrict__ A,
                                               const u16* __restrict__ Bw,
                                               OutT* __restrict__ C,
                                               int M, int N, int K) {
  __shared__ u16 As[128 * 64];
  __shared__ u16 Bs[128 * 64];
  const int t = threadIdx.x, lane = t & 63, w = t >> 6;
  const int bm0 = blockIdx.x * 128, bn0 = blockIdx.y * 128;
  const int wm = (w >> 1) * 64, wn = (w & 1) * 64;
  f32x4 acc[4][4] = {};
  for (int kt = 0; kt < K; kt += 64) {
#pragma unroll
    for (int i = 0; i < 4; ++i) {
      int offw = i * 4096 + w * 1024;
      int offl = offw + lane * 16;
      int row = offl >> 7;
      int cb  = offl & 127;
      const u16* ga = A  + (size_t)(bm0 + row) * K + kt + (cb >> 1);
      GLD_LDS16(ga, (char*)As + offw);
      const u16* gb = Bw + (size_t)(bn0 + row) * K + kt + (cb >> 1);
      GLD_LDS16(gb, (char*)Bs + offw);
    }
    __syncthreads();
#pragma unroll
    for (int kk = 0; kk < 2; ++kk) {
      const int col = kk * 32 + (lane >> 4) * 8;
      bf16x8 af[4], bfr[4];
#pragma unroll
      for (int mi = 0; mi < 4; ++mi)
        af[mi] = *(const bf16x8*)&As[(wm + mi * 16 + (lane & 15)) * 64 + col];
#pragma unroll
      for (int ni = 0; ni < 4; ++ni)
        bfr[ni] = *(const bf16x8*)&Bs[(wn + ni * 16 + (lane & 15)) * 64 + col];
#pragma unroll
      for (int mi = 0; mi < 4; ++mi)
#pragma unroll
        for (int ni = 0; ni < 4; ++ni)
          acc[mi][ni] = __builtin_amdgcn_mfma_f32_16x16x32_bf16(af[mi], bfr[ni], acc[mi][ni], 0, 0, 0);
    }
    __syncthreads();
  }
  const int r0 = (lane >> 4) * 4, cq = lane & 15;
#pragma unroll
  for (int mi = 0; mi < 4; ++mi)
#pragma unroll
    for (int ni = 0; ni < 4; ++ni) {
      size_t base = (size_t)(bm0 + wm + mi * 16 + r0) * N + bn0 + wn + ni * 16 + cq;
#pragma unroll
      for (int r = 0; r < 4; ++r) {
        float v = acc[mi][ni][r];
        if constexpr (sizeof(OutT) == 2) C[base + (size_t)r * N] = f2bf(v);
        else                             C[base + (size_t)r * N] = v;
      }
    }
}

// ---------------- rope_pack: RoPE q + RoPE k (pre-scaled) + V transpose, fused ----
// blocks [0,16384): rope_q; [16384,20480): rope_k; [20480,20992): pack_vT.
__global__ void rope_pack_kernel(const u16* __restrict__ qkv, const int* __restrict__ pid,
                                 u16* __restrict__ qb, u16* __restrict__ kb,
                                 u16* __restrict__ vT) {
  __shared__ u16 tile[64][72];
  const int bid = blockIdx.x, tid = threadIdx.x;
  if (bid < 16384) {
    int idx = bid * 256 + tid;
    int i = idx & 31;
    int s = (idx >> 5) & (Sseq - 1);
    int h = (idx >> 16) & (NH - 1);
    int b = idx >> 21;
    int row = b * Sseq + s;
    const u16* src = qkv + (size_t)row * NQKV + h * HD + i;
    float q0 = bf2f(src[0]);
    float q1 = bf2f(src[32]);
    float pos = (float)pid[row];
    float ang = pos * expf(-(float)i * (9.210340371976184f / 32.f));
    float c = cosf(ang), sn = sinf(ang);
    u16* dst = qb + ((size_t)(b * NH + h) * Sseq + s) * HD + i;
    dst[0]  = f2bf(q0 * c - q1 * sn);
    dst[32] = f2bf(q1 * c + q0 * sn);
  } else if (bid < 20480) {
    const float SCK = 0.18033688011112042f;  // log2(e)/8 folded into K
    int idx = (bid - 16384) * 256 + tid;
    int i = idx & 31;
    int s = (idx >> 5) & (Sseq - 1);
    int h = (idx >> 16) & (NKV - 1);
    int b = idx >> 19;
    int row = b * Sseq + s;
    const u16* src = qkv + (size_t)row * NQKV + 2048 + h * HD + i;
    float q0 = bf2f(src[0]);
    float q1 = bf2f(src[32]);
    float pos = (float)pid[row];
    float ang = pos * expf(-(float)i * (9.210340371976184f / 32.f));
    float c = cosf(ang), sn = sinf(ang);
    u16* dst = kb + ((size_t)(b * NKV + h) * Sseq + s) * HD + i;
    dst[0]  = f2bf((q0 * c - q1 * sn) * SCK);
    dst[32] = f2bf((q1 * c + q0 * sn) * SCK);
  } else {
    int pidx = bid - 20480;                  // [0,512)
    int s0 = (pidx & 31) * 64;
    int bh = pidx >> 5;
    int b = bh >> 3, hkv = bh & 7;
#pragma unroll
    for (int ii = 0; ii < 16; ++ii) {
      int lin = ii * 256 + tid;
      int sl = lin >> 6, d = lin & 63;
      tile[sl][d] = qkv[(size_t)(b * Sseq + s0 + sl) * NQKV + 2560 + hkv * HD + d];
    }
    __syncthreads();
#pragma unroll
    for (int ii = 0; ii < 16; ++ii) {
      int lin = ii * 256 + tid;
      int d = lin >> 6, sl = lin & 63;
      vT[((size_t)bh * HD + d) * Sseq + s0 + sl] = tile[sl][d];
    }
  }
}

// ---------------- flash attention step (round-7-proven body + T5 setprio) --------
template <bool MASKED>
__device__ __forceinline__ void attn_step(int k0, int qg, int hi, int q,
                                          const u16* __restrict__ kbp,
                                          const u16* __restrict__ vbp,
                                          const bf16x8 (&qf)[4],
                                          f32x16& o0, f32x16& o1,
                                          float& m, float& lsum) {
  bf16x8 kf0[4], kf1[4];
#pragma unroll
  for (int dk = 0; dk < 4; ++dk) {
    const u16* kp = kbp + (size_t)(k0 + q) * HD + dk * 16 + hi * 8;
    kf0[dk] = *(const bf16x8*)kp;
    kf1[dk] = *(const bf16x8*)(kp + 32 * HD);
  }
  f32x16 st0 = {}, st1 = {};
  __builtin_amdgcn_s_setprio(1);
#pragma unroll
  for (int dk = 0; dk < 4; ++dk) {
    st0 = MFMA32(kf0[dk], qf[dk], st0);
    st1 = MFMA32(kf1[dk], qf[dk], st1);
  }
  __builtin_amdgcn_s_setprio(0);
  bf16x8 vf0[4], vf1[4];
#pragma unroll
  for (int ks = 0; ks < 4; ++ks) {
    const u16* vp = vbp + (size_t)q * Sseq + k0 + ks * 16 + hi * 8;
    vf0[ks] = *(const bf16x8*)vp;
    vf1[ks] = *(const bf16x8*)(vp + 32 * Sseq);
  }
  if (MASKED) {
#pragma unroll
    for (int r = 0; r < 16; ++r) {
      const int koff = (r & 3) + 8 * (r >> 2) + 4 * hi;
      if (k0 + koff > qg)      st0[r] = -3.0e38f;
      if (k0 + 32 + koff > qg) st1[r] = -3.0e38f;
    }
  }
  // tree-reduce max (depth 5, ILP); per-half only — cross-half shfl deferred
  float t01[16];
#pragma unroll
  for (int r = 0; r < 16; ++r) t01[r] = fmaxf(st0[r], st1[r]);
#pragma unroll
  for (int s = 8; s > 0; s >>= 1)
#pragma unroll
    for (int r = 0; r < s; ++r) t01[r] = fmaxf(t01[r], t01[r + s]);
  float tmax = t01[0];
  if (__any(tmax > m + 8.f)) {                // defer-max (T13)
    float tx = fmaxf(tmax, __shfl_xor(tmax, 32));
    float mnew = fmaxf(m, tx);
    float al = exp2f(m - mnew);
    lsum *= al;
#pragma unroll
    for (int r = 0; r < 16; ++r) { o0[r] *= al; o1[r] *= al; }
    m = mnew;
  }
  float ps[16];
#pragma unroll
  for (int r = 0; r < 16; ++r) {
    float e0 = exp2f(st0[r] - m), e1 = exp2f(st1[r] - m);
    st0[r] = e0; st1[r] = e1;
    ps[r] = e0 + e1;
  }
#pragma unroll
  for (int s = 8; s > 0; s >>= 1)
#pragma unroll
    for (int r = 0; r < s; ++r) ps[r] += ps[r + s];
  lsum += ps[0];                 // lane-partial; cross-half combine in epilogue
  // P -> bf16 fragments via cvt_pk + permlane32_swap (T12; round-2-proven)
  bf16x8 pa[4];
#pragma unroll
  for (int ks = 0; ks < 4; ++ks) {
    const int sel = (ks & 1) * 8;
    f32x16& stt = (ks < 2) ? st0 : st1;
    uint32_t X0, Y0, X1, Y1;
    asm("v_cvt_pk_bf16_f32 %0, %1, %2" : "=v"(X0) : "v"(stt[sel + 0]), "v"(stt[sel + 1]));
    asm("v_cvt_pk_bf16_f32 %0, %1, %2" : "=v"(Y0) : "v"(stt[sel + 4]), "v"(stt[sel + 5]));
    asm("v_cvt_pk_bf16_f32 %0, %1, %2" : "=v"(X1) : "v"(stt[sel + 2]), "v"(stt[sel + 3]));
    asm("v_cvt_pk_bf16_f32 %0, %1, %2" : "=v"(Y1) : "v"(stt[sel + 6]), "v"(stt[sel + 7]));
    asm volatile("v_permlane32_swap_b32 %0, %1" : "+v"(X0), "+v"(Y0));
    asm volatile("v_permlane32_swap_b32 %0, %1" : "+v"(X1), "+v"(Y1));
    union { uint32_t w[4]; bf16x8 v; } u_;
    u_.w[0] = X0; u_.w[1] = X1; u_.w[2] = Y0; u_.w[3] = Y1;
    pa[ks] = u_.v;
  }
  __builtin_amdgcn_s_setprio(1);
#pragma unroll
  for (int ks = 0; ks < 4; ++ks) {
    o0 = MFMA32(vf0[ks], pa[ks], o0);
    o1 = MFMA32(vf1[ks], pa[ks], o1);
  }
  __builtin_amdgcn_s_setprio(0);
}

// 1024 blocks x 4 waves. Work map: ROUND-7-PROVEN (135 µs, twice) — g = bid*4+wid,
// bh = g&63 (4 consecutive heads share one KV stream), qt = 63-(g>>6) heavy-first.
// R5/R6/R9 "balance" remaps all regressed; placement is unknowable — keep this.
__global__ __launch_bounds__(256) void attn_kernel(const u16* __restrict__ qb,
                                                   const u16* __restrict__ kb,
                                                   const u16* __restrict__ vT,
                                                   u16* __restrict__ aout) {
  __shared__ uint32_t ldso[4][32 * 33];
  const int tid = threadIdx.x;
  const int lane = tid & 63, wid = tid >> 6;
  const int q = lane & 31, hi = lane >> 5;
  const int g = blockIdx.x * 4 + wid;
  const int bh = g & 63;
  const int qt = 63 - (g >> 6);
  const int b = bh >> 5, h = bh & 31, hkv = h >> 2;
  const int qbase = qt * 32, qg = qbase + q;

  const u16* qp = qb + ((size_t)bh * Sseq + qg) * HD + hi * 8;
  bf16x8 qf[4];
#pragma unroll
  for (int dk = 0; dk < 4; ++dk) qf[dk] = *(const bf16x8*)(qp + dk * 16);

  const u16* kbp = kb + (size_t)(b * NKV + hkv) * Sseq * HD;
  const u16* vbp = vT + (size_t)(b * NKV + hkv) * HD * Sseq;

  f32x16 o0 = {}, o1 = {};
  float m = -INFINITY, lsum = 0.f;
  const int ntiles = (qt >> 1) + 1;

  for (int kt = 0; kt < ntiles - 1; ++kt)
    attn_step<false>(kt * 64, qg, hi, q, kbp, vbp, qf, o0, o1, m, lsum);
  attn_step<true>((ntiles - 1) * 64, qg, hi, q, kbp, vbp, qf, o0, o1, m, lsum);

  lsum += __shfl_xor(lsum, 32);        // cross-half lsum combine
  const float inv = 1.f / lsum;

  // epilogue transpose via packed-bf16 u32 LDS (16.9 KB/block)
  uint32_t* lw = ldso[wid];
#pragma unroll
  for (int rr = 0; rr < 16; rr += 2) {
    const int d2 = ((rr >> 1) & 1) + 4 * (rr >> 2) + 2 * hi;
    uint32_t w0, w1;
    asm("v_cvt_pk_bf16_f32 %0, %1, %2" : "=v"(w0) : "v"(o0[rr] * inv), "v"(o0[rr + 1] * inv));
    asm("v_cvt_pk_bf16_f32 %0, %1, %2" : "=v"(w1) : "v"(o1[rr] * inv), "v"(o1[rr + 1] * inv));
    lw[d2 * 33 + q]        = w0;
    lw[(16 + d2) * 33 + q] = w1;
  }
  asm volatile("s_waitcnt lgkmcnt(0)" ::: "memory");
  __builtin_amdgcn_sched_barrier(0);
  uint32_t wv[16];
#pragma unroll
  for (int jj = 0; jj < 16; ++jj) wv[jj] = lw[(hi * 16 + jj) * 33 + q];
  uint4* op4 = (uint4*)(aout + (size_t)(b * Sseq + qbase + q) * (NH * HD) + h * HD + hi * 32);
#pragma unroll
  for (int k4 = 0; k4 < 4; ++k4)
    op4[k4] = make_uint4(wv[4 * k4], wv[4 * k4 + 1], wv[4 * k4 + 2], wv[4 * k4 + 3]);
}

extern "C" void kernel_launch(void* const* d_in, const int* in_sizes, int n_in,
                              void* d_out, int out_size, void* d_ws, size_t ws_size,
                              hipStream_t stream) {
  const float* x  = (const float*)d_in[0];
  const int*   pid= (const int*)d_in[1];
  const float* Wq = (const float*)d_in[2];
  const float* Wk = (const float*)d_in[3];
  const float* Wv = (const float*)d_in[4];
  const float* Wo = (const float*)d_in[5];
  const float* Aq = (const float*)d_in[6];
  const float* Bq = (const float*)d_in[7];
  const float* Ak = (const float*)d_in[8];
  const float* Bk = (const float*)d_in[9];
  const float* Av = (const float*)d_in[10];
  const float* Bv = (const float*)d_in[11];
  const float* Ao = (const float*)d_in[12];
  const float* Bo = (const float*)d_in[13];
  float* out = (float*)d_out;

  char* w = (char*)d_ws;
  u16*   x_bf    = (u16*)w;   w += (size_t)Mrows * Hdim * 2;
  u16*   weffqkv = (u16*)w;   w += (size_t)NQKV * Hdim * 2;
  u16*   weffo   = (u16*)w;   w += (size_t)Hdim * Hdim * 2;
  u16*   qkv     = (u16*)w;   w += (size_t)Mrows * NQKV * 2;
  u16*   qbb     = (u16*)w;   w += (size_t)Bsz * NH * Sseq * HD * 2;
  u16*   kbb     = (u16*)w;   w += (size_t)Bsz * NKV * Sseq * HD * 2;
  u16*   vTb     = (u16*)w;   w += (size_t)Bsz * NKV * Sseq * HD * 2;
  u16*   aoutb   = (u16*)w;   w += (size_t)Mrows * (NH * HD) * 2;

  prep_kernel<<<49152, 256, 0, stream>>>(x, x_bf,
                                         Wq, Aq, Bq, Wk, Ak, Bk, Wv, Av, Bv, Wo, Ao, Bo,
                                         weffqkv, weffo);

  gemm_bt<u16><<<dim3(32, 24), 256, 0, stream>>>(x_bf, weffqkv, qkv, Mrows, NQKV, Hdim);

  rope_pack_kernel<<<20992, 256, 0, stream>>>(qkv, pid, qbb, kbb, vTb);

  attn_kernel<<<1024, 256, 0, stream>>>(qbb, kbb, vTb, aoutb);

  gemm_bt<float><<<dim3(32, 16), 256, 0, stream>>>(aoutb, weffo, out, Mrows, 2048, 2048);
}

// Round 11
// 282.408 us; speedup vs baseline: 1.3260x; 1.1773x over previous
//
#include <hip/hip_runtime.h>
#include <stdint.h>

#define Bsz 2
#define Sseq 2048
#define Hdim 2048
#define NH 32
#define NKV 8
#define HD 64
#define RANKD 16
#define LSCALE (1.0f/16.0f)
#define Mrows (Bsz*Sseq)      // 4096
#define NQKV 3072             // 2048 q + 512 k + 512 v

typedef unsigned short u16;
typedef __bf16 bf16x8 __attribute__((ext_vector_type(8)));
typedef float f32x4 __attribute__((ext_vector_type(4)));
typedef float f32x16 __attribute__((ext_vector_type(16)));

#define MFMA32(A, B, C) __builtin_amdgcn_mfma_f32_32x32x16_bf16(A, B, C, 0, 0, 0)

__device__ __forceinline__ u16 f2bf(float f) {
  union { float f; uint32_t u; } v; v.f = f;
  uint32_t u = v.u;
  return (u16)((u + 0x7fffu + ((u >> 16) & 1u)) >> 16);   // round-nearest-even
}
__device__ __forceinline__ float bf2f(u16 b) {
  union { uint32_t u; float f; } v; v.u = ((uint32_t)b) << 16;
  return v.f;
}

#define GLD_LDS16(g, l) \
  __builtin_amdgcn_global_load_lds((const __attribute__((address_space(1))) void*)(g), \
                                   (__attribute__((address_space(3))) void*)(l), 16, 0, 0)

// ---------------- prep: 4x W_eff (bf16) + x f32->bf16, fused ----------------
__global__ void prep_kernel(const float* __restrict__ x, u16* __restrict__ x_bf,
                            const float* __restrict__ Wq, const float* __restrict__ Aq, const float* __restrict__ Bq,
                            const float* __restrict__ Wk, const float* __restrict__ Ak, const float* __restrict__ Bk,
                            const float* __restrict__ Wv, const float* __restrict__ Av, const float* __restrict__ Bv,
                            const float* __restrict__ Wo, const float* __restrict__ Ao, const float* __restrict__ Bo,
                            u16* __restrict__ weffqkv, u16* __restrict__ weffo) {
  __shared__ float bcol[RANKD];
  const int bid = blockIdx.x, tid = threadIdx.x;
  if (bid < 40960) {
    const int y = bid >> 3;
    const int k = (bid & 7) * 256 + tid;
    const float *W, *A, *Bm;
    u16* out;
    int N, n;
    if (y < 2048)      { W = Wq; A = Aq; Bm = Bq; out = weffqkv;                         N = 2048; n = y; }
    else if (y < 2560) { W = Wk; A = Ak; Bm = Bk; out = weffqkv + (size_t)2048 * Hdim;   N = 512;  n = y - 2048; }
    else if (y < 3072) { W = Wv; A = Av; Bm = Bv; out = weffqkv + (size_t)2560 * Hdim;   N = 512;  n = y - 2560; }
    else               { W = Wo; A = Ao; Bm = Bo; out = weffo;                           N = 2048; n = y - 3072; }
    if (tid < RANKD) bcol[tid] = Bm[tid * N + n];
    __syncthreads();
    float acc = 0.f;
#pragma unroll
    for (int r = 0; r < RANKD; ++r) acc += A[k * RANKD + r] * bcol[r];
    out[(size_t)n * Hdim + k] = f2bf(W[(size_t)n * Hdim + k] + acc * LSCALE);
  } else {
    const int i = (bid - 40960) * 256 + tid;
    float4 v = ((const float4*)x)[i];
    ushort4 o;
    o.x = f2bf(v.x); o.y = f2bf(v.y); o.z = f2bf(v.z); o.w = f2bf(v.w);
    ((ushort4*)x_bf)[i] = o;
  }
}

// ---------------- bf16 GEMM, B-transposed layout (m97 structure) ----------------
template <typename OutT>
__global__ __launch_bounds__(256) void gemm_bt(const u16* __restrict__ A,
                                               const u16* __restrict__ Bw,
                                               OutT* __restrict__ C,
                                               int M, int N, int K) {
  __shared__ u16 As[128 * 64];
  __shared__ u16 Bs[128 * 64];
  const int t = threadIdx.x, lane = t & 63, w = t >> 6;
  const int bm0 = blockIdx.x * 128, bn0 = blockIdx.y * 128;
  const int wm = (w >> 1) * 64, wn = (w & 1) * 64;
  f32x4 acc[4][4] = {};
  for (int kt = 0; kt < K; kt += 64) {
#pragma unroll
    for (int i = 0; i < 4; ++i) {
      int offw = i * 4096 + w * 1024;
      int offl = offw + lane * 16;
      int row = offl >> 7;
      int cb  = offl & 127;
      const u16* ga = A  + (size_t)(bm0 + row) * K + kt + (cb >> 1);
      GLD_LDS16(ga, (char*)As + offw);
      const u16* gb = Bw + (size_t)(bn0 + row) * K + kt + (cb >> 1);
      GLD_LDS16(gb, (char*)Bs + offw);
    }
    __syncthreads();
#pragma unroll
    for (int kk = 0; kk < 2; ++kk) {
      const int col = kk * 32 + (lane >> 4) * 8;
      bf16x8 af[4], bfr[4];
#pragma unroll
      for (int mi = 0; mi < 4; ++mi)
        af[mi] = *(const bf16x8*)&As[(wm + mi * 16 + (lane & 15)) * 64 + col];
#pragma unroll
      for (int ni = 0; ni < 4; ++ni)
        bfr[ni] = *(const bf16x8*)&Bs[(wn + ni * 16 + (lane & 15)) * 64 + col];
#pragma unroll
      for (int mi = 0; mi < 4; ++mi)
#pragma unroll
        for (int ni = 0; ni < 4; ++ni)
          acc[mi][ni] = __builtin_amdgcn_mfma_f32_16x16x32_bf16(af[mi], bfr[ni], acc[mi][ni], 0, 0, 0);
    }
    __syncthreads();
  }
  const int r0 = (lane >> 4) * 4, cq = lane & 15;
#pragma unroll
  for (int mi = 0; mi < 4; ++mi)
#pragma unroll
    for (int ni = 0; ni < 4; ++ni) {
      size_t base = (size_t)(bm0 + wm + mi * 16 + r0) * N + bn0 + wn + ni * 16 + cq;
#pragma unroll
      for (int r = 0; r < 4; ++r) {
        float v = acc[mi][ni][r];
        if constexpr (sizeof(OutT) == 2) C[base + (size_t)r * N] = f2bf(v);
        else                             C[base + (size_t)r * N] = v;
      }
    }
}

// ---------------- rope_pack: RoPE q + RoPE k (pre-scaled) + V pack, fused --------
// V now packed TILE-MAJOR: vT[((bh*32 + s0/64)*HD + d)*64 + (s-s0)] so each
// 64-key V^T tile is one contiguous 8 KB block (for coalesced global_load_lds).
__global__ void rope_pack_kernel(const u16* __restrict__ qkv, const int* __restrict__ pid,
                                 u16* __restrict__ qb, u16* __restrict__ kb,
                                 u16* __restrict__ vT) {
  __shared__ u16 tile[64][72];
  const int bid = blockIdx.x, tid = threadIdx.x;
  if (bid < 16384) {
    int idx = bid * 256 + tid;
    int i = idx & 31;
    int s = (idx >> 5) & (Sseq - 1);
    int h = (idx >> 16) & (NH - 1);
    int b = idx >> 21;
    int row = b * Sseq + s;
    const u16* src = qkv + (size_t)row * NQKV + h * HD + i;
    float q0 = bf2f(src[0]);
    float q1 = bf2f(src[32]);
    float pos = (float)pid[row];
    float ang = pos * expf(-(float)i * (9.210340371976184f / 32.f));
    float c = cosf(ang), sn = sinf(ang);
    u16* dst = qb + ((size_t)(b * NH + h) * Sseq + s) * HD + i;
    dst[0]  = f2bf(q0 * c - q1 * sn);
    dst[32] = f2bf(q1 * c + q0 * sn);
  } else if (bid < 20480) {
    const float SCK = 0.18033688011112042f;  // log2(e)/8 folded into K
    int idx = (bid - 16384) * 256 + tid;
    int i = idx & 31;
    int s = (idx >> 5) & (Sseq - 1);
    int h = (idx >> 16) & (NKV - 1);
    int b = idx >> 19;
    int row = b * Sseq + s;
    const u16* src = qkv + (size_t)row * NQKV + 2048 + h * HD + i;
    float q0 = bf2f(src[0]);
    float q1 = bf2f(src[32]);
    float pos = (float)pid[row];
    float ang = pos * expf(-(float)i * (9.210340371976184f / 32.f));
    float c = cosf(ang), sn = sinf(ang);
    u16* dst = kb + ((size_t)(b * NKV + h) * Sseq + s) * HD + i;
    dst[0]  = f2bf((q0 * c - q1 * sn) * SCK);
    dst[32] = f2bf((q1 * c + q0 * sn) * SCK);
  } else {
    int pidx = bid - 20480;                  // [0,512)
    int s0 = (pidx & 31) * 64;
    int bh = pidx >> 5;
    int b = bh >> 3, hkv = bh & 7;
#pragma unroll
    for (int ii = 0; ii < 16; ++ii) {
      int lin = ii * 256 + tid;
      int sl = lin >> 6, d = lin & 63;
      tile[sl][d] = qkv[(size_t)(b * Sseq + s0 + sl) * NQKV + 2560 + hkv * HD + d];
    }
    __syncthreads();
#pragma unroll
    for (int ii = 0; ii < 16; ++ii) {
      int lin = ii * 256 + tid;
      int d = lin >> 6, sl = lin & 63;
      vT[((size_t)(bh * 32 + (s0 >> 6)) * HD + d) * 64 + sl] = tile[sl][d];
    }
  }
}

// ---------------- attn: LDS-staged K/V (coalesced) + swizzled ds_read ----------
// Stage one 8KB K-tile + 8KB V-tile per block-step with global_load_lds:
// linear LDS dest, per-lane INVERSE-swizzled global source (swz is an XOR
// involution: o ^= ((o>>7)&7)<<4), swizzled ds_read -> bank-conflict floor.
__device__ __forceinline__ void stage_kv(const char* gK, const char* gV,
                                         char* lK, char* lV, int wid, int lane) {
#pragma unroll
  for (int i = 0; i < 2; ++i) {
    int base = wid * 1024 + i * 4096;
    int lo = base + lane * 16;
    int so = lo ^ (((lo >> 7) & 7) << 4);
    GLD_LDS16(gK + so, lK + base);
    GLD_LDS16(gV + so, lV + base);
  }
}

template <bool MASKED>
__device__ __forceinline__ void attn_step(int k0, int qg, int hi, int q,
                                          const char* __restrict__ lK,
                                          const char* __restrict__ lV,
                                          const bf16x8 (&qf)[4],
                                          f32x16& o0, f32x16& o1,
                                          float& m, float& lsum) {
  // swizzled fragment addresses: row q (and q+32 at +4096B), col bits 4-6 XOR'd
  bf16x8 kf0[4], kf1[4];
#pragma unroll
  for (int dk = 0; dk < 4; ++dk) {
    int a = (q << 7) | (((dk << 5) | (hi << 4)) ^ ((q & 7) << 4));
    kf0[dk] = *(const bf16x8*)(lK + a);
    kf1[dk] = *(const bf16x8*)(lK + a + 4096);
  }
  f32x16 st0 = {}, st1 = {};
  __builtin_amdgcn_s_setprio(1);
#pragma unroll
  for (int dk = 0; dk < 4; ++dk) {
    st0 = MFMA32(kf0[dk], qf[dk], st0);
    st1 = MFMA32(kf1[dk], qf[dk], st1);
  }
  __builtin_amdgcn_s_setprio(0);
  bf16x8 vf0[4], vf1[4];
#pragma unroll
  for (int ks = 0; ks < 4; ++ks) {
    int a = (q << 7) | (((ks << 5) | (hi << 4)) ^ ((q & 7) << 4));
    vf0[ks] = *(const bf16x8*)(lV + a);
    vf1[ks] = *(const bf16x8*)(lV + a + 4096);
  }
  if (MASKED) {
#pragma unroll
    for (int r = 0; r < 16; ++r) {
      const int koff = (r & 3) + 8 * (r >> 2) + 4 * hi;
      if (k0 + koff > qg)      st0[r] = -3.0e38f;
      if (k0 + 32 + koff > qg) st1[r] = -3.0e38f;
    }
  }
  // tree-reduce max (depth 5, ILP); per-half only — cross-half shfl deferred
  float t01[16];
#pragma unroll
  for (int r = 0; r < 16; ++r) t01[r] = fmaxf(st0[r], st1[r]);
#pragma unroll
  for (int s = 8; s > 0; s >>= 1)
#pragma unroll
    for (int r = 0; r < s; ++r) t01[r] = fmaxf(t01[r], t01[r + s]);
  float tmax = t01[0];
  if (__any(tmax > m + 8.f)) {                // defer-max (T13)
    float tx = fmaxf(tmax, __shfl_xor(tmax, 32));
    float mnew = fmaxf(m, tx);
    float al = exp2f(m - mnew);
    lsum *= al;
#pragma unroll
    for (int r = 0; r < 16; ++r) { o0[r] *= al; o1[r] *= al; }
    m = mnew;
  }
  float ps[16];
#pragma unroll
  for (int r = 0; r < 16; ++r) {
    float e0 = exp2f(st0[r] - m), e1 = exp2f(st1[r] - m);
    st0[r] = e0; st1[r] = e1;
    ps[r] = e0 + e1;
  }
#pragma unroll
  for (int s = 8; s > 0; s >>= 1)
#pragma unroll
    for (int r = 0; r < s; ++r) ps[r] += ps[r + s];
  lsum += ps[0];                 // lane-partial; cross-half combine in epilogue
  // P -> bf16 fragments via cvt_pk + permlane32_swap (T12; round-2-proven)
  bf16x8 pa[4];
#pragma unroll
  for (int ks = 0; ks < 4; ++ks) {
    const int sel = (ks & 1) * 8;
    f32x16& stt = (ks < 2) ? st0 : st1;
    uint32_t X0, Y0, X1, Y1;
    asm("v_cvt_pk_bf16_f32 %0, %1, %2" : "=v"(X0) : "v"(stt[sel + 0]), "v"(stt[sel + 1]));
    asm("v_cvt_pk_bf16_f32 %0, %1, %2" : "=v"(Y0) : "v"(stt[sel + 4]), "v"(stt[sel + 5]));
    asm("v_cvt_pk_bf16_f32 %0, %1, %2" : "=v"(X1) : "v"(stt[sel + 2]), "v"(stt[sel + 3]));
    asm("v_cvt_pk_bf16_f32 %0, %1, %2" : "=v"(Y1) : "v"(stt[sel + 6]), "v"(stt[sel + 7]));
    asm volatile("v_permlane32_swap_b32 %0, %1" : "+v"(X0), "+v"(Y0));
    asm volatile("v_permlane32_swap_b32 %0, %1" : "+v"(X1), "+v"(Y1));
    union { uint32_t w[4]; bf16x8 v; } u_;
    u_.w[0] = X0; u_.w[1] = X1; u_.w[2] = Y0; u_.w[3] = Y1;
    pa[ks] = u_.v;
  }
  __builtin_amdgcn_s_setprio(1);
#pragma unroll
  for (int ks = 0; ks < 4; ++ks) {
    o0 = MFMA32(vf0[ks], pa[ks], o0);
    o1 = MFMA32(vf1[ks], pa[ks], o1);
  }
  __builtin_amdgcn_s_setprio(0);
}

// 1024 blocks x 4 waves; ROUND-7-PROVEN work map. The 4 waves of a block share
// hkv and qt, so K/V tiles are staged ONCE per block-step and consumed by all.
__global__ __launch_bounds__(256) void attn_kernel(const u16* __restrict__ qb,
                                                   const u16* __restrict__ kb,
                                                   const u16* __restrict__ vT,
                                                   u16* __restrict__ aout) {
  __shared__ __align__(16) char smem[32768];   // K dbuf 16K + V dbuf 16K; epilogue aliases
  const int tid = threadIdx.x;
  const int lane = tid & 63, wid = tid >> 6;
  const int q = lane & 31, hi = lane >> 5;
  const int g = blockIdx.x * 4 + wid;
  const int bh = g & 63;
  const int qt = 63 - (g >> 6);
  const int b = bh >> 5, h = bh & 31, hkv = h >> 2;
  const int qbase = qt * 32, qg = qbase + q;

  const u16* qp = qb + ((size_t)bh * Sseq + qg) * HD + hi * 8;
  bf16x8 qf[4];
#pragma unroll
  for (int dk = 0; dk < 4; ++dk) qf[dk] = *(const bf16x8*)(qp + dk * 16);

  const char* gK = (const char*)(kb + (size_t)(b * NKV + hkv) * Sseq * HD);
  const char* gV = (const char*)(vT + (size_t)(b * NKV + hkv) * Sseq * HD);

  f32x16 o0 = {}, o1 = {};
  float m = -INFINITY, lsum = 0.f;
  const int ntiles = (qt >> 1) + 1;

  stage_kv(gK, gV, smem, smem + 16384, wid, lane);
  __syncthreads();
  int cur = 0;
  for (int kt = 0; kt < ntiles - 1; ++kt) {
    int nxt = cur ^ 1;
    stage_kv(gK + (size_t)(kt + 1) * 8192, gV + (size_t)(kt + 1) * 8192,
             smem + nxt * 8192, smem + 16384 + nxt * 8192, wid, lane);
    attn_step<false>(kt * 64, qg, hi, q, smem + cur * 8192,
                     smem + 16384 + cur * 8192, qf, o0, o1, m, lsum);
    __syncthreads();     // drains vmcnt (stage complete) + all waves done reading
    cur = nxt;
  }
  attn_step<true>((ntiles - 1) * 64, qg, hi, q, smem + cur * 8192,
                  smem + 16384 + cur * 8192, qf, o0, o1, m, lsum);
  __syncthreads();       // staging buffers dead; epilogue aliases smem

  lsum += __shfl_xor(lsum, 32);        // cross-half lsum combine
  const float inv = 1.f / lsum;

  // epilogue transpose via packed-bf16 u32 LDS (aliased into smem)
  uint32_t* lw = (uint32_t*)smem + wid * (32 * 33);
#pragma unroll
  for (int rr = 0; rr < 16; rr += 2) {
    const int d2 = ((rr >> 1) & 1) + 4 * (rr >> 2) + 2 * hi;
    uint32_t w0, w1;
    asm("v_cvt_pk_bf16_f32 %0, %1, %2" : "=v"(w0) : "v"(o0[rr] * inv), "v"(o0[rr + 1] * inv));
    asm("v_cvt_pk_bf16_f32 %0, %1, %2" : "=v"(w1) : "v"(o1[rr] * inv), "v"(o1[rr + 1] * inv));
    lw[d2 * 33 + q]        = w0;
    lw[(16 + d2) * 33 + q] = w1;
  }
  asm volatile("s_waitcnt lgkmcnt(0)" ::: "memory");
  __builtin_amdgcn_sched_barrier(0);
  uint32_t wv[16];
#pragma unroll
  for (int jj = 0; jj < 16; ++jj) wv[jj] = lw[(hi * 16 + jj) * 33 + q];
  uint4* op4 = (uint4*)(aout + (size_t)(b * Sseq + qbase + q) * (NH * HD) + h * HD + hi * 32);
#pragma unroll
  for (int k4 = 0; k4 < 4; ++k4)
    op4[k4] = make_uint4(wv[4 * k4], wv[4 * k4 + 1], wv[4 * k4 + 2], wv[4 * k4 + 3]);
}

extern "C" void kernel_launch(void* const* d_in, const int* in_sizes, int n_in,
                              void* d_out, int out_size, void* d_ws, size_t ws_size,
                              hipStream_t stream) {
  const float* x  = (const float*)d_in[0];
  const int*   pid= (const int*)d_in[1];
  const float* Wq = (const float*)d_in[2];
  const float* Wk = (const float*)d_in[3];
  const float* Wv = (const float*)d_in[4];
  const float* Wo = (const float*)d_in[5];
  const float* Aq = (const float*)d_in[6];
  const float* Bq = (const float*)d_in[7];
  const float* Ak = (const float*)d_in[8];
  const float* Bk = (const float*)d_in[9];
  const float* Av = (const float*)d_in[10];
  const float* Bv = (const float*)d_in[11];
  const float* Ao = (const float*)d_in[12];
  const float* Bo = (const float*)d_in[13];
  float* out = (float*)d_out;

  char* w = (char*)d_ws;
  u16*   x_bf    = (u16*)w;   w += (size_t)Mrows * Hdim * 2;
  u16*   weffqkv = (u16*)w;   w += (size_t)NQKV * Hdim * 2;
  u16*   weffo   = (u16*)w;   w += (size_t)Hdim * Hdim * 2;
  u16*   qkv     = (u16*)w;   w += (size_t)Mrows * NQKV * 2;
  u16*   qbb     = (u16*)w;   w += (size_t)Bsz * NH * Sseq * HD * 2;
  u16*   kbb     = (u16*)w;   w += (size_t)Bsz * NKV * Sseq * HD * 2;
  u16*   vTb     = (u16*)w;   w += (size_t)Bsz * NKV * Sseq * HD * 2;
  u16*   aoutb   = (u16*)w;   w += (size_t)Mrows * (NH * HD) * 2;

  prep_kernel<<<49152, 256, 0, stream>>>(x, x_bf,
                                         Wq, Aq, Bq, Wk, Ak, Bk, Wv, Av, Bv, Wo, Ao, Bo,
                                         weffqkv, weffo);

  gemm_bt<u16><<<dim3(32, 24), 256, 0, stream>>>(x_bf, weffqkv, qkv, Mrows, NQKV, Hdim);

  rope_pack_kernel<<<20992, 256, 0, stream>>>(qkv, pid, qbb, kbb, vTb);

  attn_kernel<<<1024, 256, 0, stream>>>(qbb, kbb, vTb, aoutb);

  gemm_bt<float><<<dim3(32, 16), 256, 0, stream>>>(aoutb, weffo, out, Mrows, 2048, 2048);
}

// Round 12
// 247.866 us; speedup vs baseline: 1.5108x; 1.1394x over previous
//
#include <hip/hip_runtime.h>
#include <stdint.h>

#define Bsz 2
#define Sseq 2048
#define Hdim 2048
#define NH 32
#define NKV 8
#define HD 64
#define RANKD 16
#define LSCALE (1.0f/16.0f)
#define Mrows (Bsz*Sseq)      // 4096
#define NQKV 3072             // 2048 q + 512 k + 512 v

typedef unsigned short u16;
typedef __bf16 bf16x8 __attribute__((ext_vector_type(8)));
typedef float f32x4 __attribute__((ext_vector_type(4)));
typedef float f32x16 __attribute__((ext_vector_type(16)));

#define MFMA32(A, B, C) __builtin_amdgcn_mfma_f32_32x32x16_bf16(A, B, C, 0, 0, 0)
#define MFMA16(A, B, C) __builtin_amdgcn_mfma_f32_16x16x32_bf16(A, B, C, 0, 0, 0)

__device__ __forceinline__ u16 f2bf(float f) {
  union { float f; uint32_t u; } v; v.f = f;
  uint32_t u = v.u;
  return (u16)((u + 0x7fffu + ((u >> 16) & 1u)) >> 16);   // round-nearest-even
}
__device__ __forceinline__ float bf2f(u16 b) {
  union { uint32_t u; float f; } v; v.u = ((uint32_t)b) << 16;
  return v.f;
}

#define GLD_LDS16(g, l) \
  __builtin_amdgcn_global_load_lds((const __attribute__((address_space(1))) void*)(g), \
                                   (__attribute__((address_space(3))) void*)(l), 16, 0, 0)

// ---------------- prep: 4x W_eff (bf16) + x f32->bf16, fused ----------------
__global__ void prep_kernel(const float* __restrict__ x, u16* __restrict__ x_bf,
                            const float* __restrict__ Wq, const float* __restrict__ Aq, const float* __restrict__ Bq,
                            const float* __restrict__ Wk, const float* __restrict__ Ak, const float* __restrict__ Bk,
                            const float* __restrict__ Wv, const float* __restrict__ Av, const float* __restrict__ Bv,
                            const float* __restrict__ Wo, const float* __restrict__ Ao, const float* __restrict__ Bo,
                            u16* __restrict__ weffqkv, u16* __restrict__ weffo) {
  __shared__ float bcol[RANKD];
  const int bid = blockIdx.x, tid = threadIdx.x;
  if (bid < 40960) {
    const int y = bid >> 3;
    const int k = (bid & 7) * 256 + tid;
    const float *W, *A, *Bm;
    u16* out;
    int N, n;
    if (y < 2048)      { W = Wq; A = Aq; Bm = Bq; out = weffqkv;                         N = 2048; n = y; }
    else if (y < 2560) { W = Wk; A = Ak; Bm = Bk; out = weffqkv + (size_t)2048 * Hdim;   N = 512;  n = y - 2048; }
    else if (y < 3072) { W = Wv; A = Av; Bm = Bv; out = weffqkv + (size_t)2560 * Hdim;   N = 512;  n = y - 2560; }
    else               { W = Wo; A = Ao; Bm = Bo; out = weffo;                           N = 2048; n = y - 3072; }
    if (tid < RANKD) bcol[tid] = Bm[tid * N + n];
    __syncthreads();
    float acc = 0.f;
#pragma unroll
    for (int r = 0; r < RANKD; ++r) acc += A[k * RANKD + r] * bcol[r];
    out[(size_t)n * Hdim + k] = f2bf(W[(size_t)n * Hdim + k] + acc * LSCALE);
  } else {
    const int i = (bid - 40960) * 256 + tid;
    float4 v = ((const float4*)x)[i];
    ushort4 o;
    o.x = f2bf(v.x); o.y = f2bf(v.y); o.z = f2bf(v.z); o.w = f2bf(v.w);
    ((ushort4*)x_bf)[i] = o;
  }
}

// ---------------- 256x256 8-phase bf16 GEMM (T2+T3+T4+T5) ----------------
// A [M,K] bf16 row-major, Bw [N,K] bf16 row-major (B^T), C [M,N].
// 512 thr = 8 waves (2M x 4N); per-wave C = 128x64 = acc[8][4] f32x4.
// LDS 128 KB: 2 K-tile buffers x {A,B} x 2 K-halves (16 KB slots).
// Slot: 256 rows x 32 bf16 (64 B rows); swizzle c ^= ((row>>1)&3)<<4 (rule #21:
// linear gload_lds dest + inverse-swizzled global src + swizzled ds_read).
// Counted vmcnt(4) at ph3/ph7 only (T4); stages never drain to 0 in-loop.
#define GSWZ(lo) ((lo) ^ ((((lo) >> 7) & 3) << 4))
#define RSWZ(r)  ((((r) >> 1) & 3) << 4)

#define G_STAGE(G, buf, matoff, kh, t)                                                     \
  { _Pragma("unroll") for (int ii = 0; ii < 2; ++ii) {                                     \
      int lo = ii * 8192 + wid * 1024 + lane * 16;                                         \
      int so = GSWZ(lo);                                                                   \
      GLD_LDS16((const char*)(G) + (size_t)(so >> 6) * K2 + (t) * 128 + (kh) * 64 + (so & 63), \
                sm + (buf) * 65536 + (matoff) + (kh) * 16384 + ii * 8192 + wid * 1024);    \
  } }

#define RD_A(buf, kk)                                                                      \
  { _Pragma("unroll") for (int mi = 0; mi < 8; ++mi) {                                     \
      int rA = wm * 128 + mi * 16 + lr;                                                    \
      af[mi] = *(const bf16x8*)(sm + (buf) * 65536 + (kk) * 16384 + rA * 64 +              \
                                ((qw * 16) ^ RSWZ(rA)));                                   \
  } }

#define RD_B(buf, kk, n0)                                                                  \
  { int rB0 = wn * 64 + (n0) * 16 + lr;                                                    \
    int rB1 = rB0 + 16;                                                                    \
    b0 = *(const bf16x8*)(sm + (buf) * 65536 + 32768 + (kk) * 16384 + rB0 * 64 +           \
                          ((qw * 16) ^ RSWZ(rB0)));                                        \
    b1 = *(const bf16x8*)(sm + (buf) * 65536 + 32768 + (kk) * 16384 + rB1 * 64 +           \
                          ((qw * 16) ^ RSWZ(rB1))); }

#define MMQ(n0)                                                                            \
  __builtin_amdgcn_s_setprio(1);                                                           \
  _Pragma("unroll") for (int mi = 0; mi < 8; ++mi) {                                       \
    acc[mi][(n0)]     = MFMA16(af[mi], b0, acc[mi][(n0)]);                                 \
    acc[mi][(n0) + 1] = MFMA16(af[mi], b1, acc[mi][(n0) + 1]);                             \
  }                                                                                        \
  __builtin_amdgcn_s_setprio(0);

#define GBAR() __builtin_amdgcn_sched_barrier(0); __builtin_amdgcn_s_barrier(); \
               __builtin_amdgcn_sched_barrier(0)

template <typename OutT>
__global__ __launch_bounds__(512, 2) void gemm256(const u16* __restrict__ A,
                                                  const u16* __restrict__ Bw,
                                                  OutT* __restrict__ C,
                                                  int M, int N, int K) {
  __shared__ __align__(16) char sm[131072];
  const int tid = threadIdx.x;
  const int lane = tid & 63, wid = tid >> 6;
  const int wm = wid >> 2, wn = wid & 3;
  const int lr = lane & 15, qw = lane >> 4;
  const int bm0 = blockIdx.x * 256, bn0 = blockIdx.y * 256;
  const int K2 = K * 2;
  const int NT = K >> 6;                 // 64-wide K-tiles (even count)
  const u16* gA = A + (size_t)bm0 * K;
  const u16* gB = Bw + (size_t)bn0 * K;

  f32x4 acc[8][4] = {};
  bf16x8 af[8], b0, b1;

  // prologue: stage t0 fully (X=buf0) + t1's K-half0 (Y=buf1)
  G_STAGE(gA, 0, 0,     0, 0)  G_STAGE(gB, 0, 32768, 0, 0)
  G_STAGE(gA, 0, 0,     1, 0)  G_STAGE(gB, 0, 32768, 1, 0)
  G_STAGE(gA, 1, 0,     0, 1)  G_STAGE(gB, 1, 32768, 0, 1)
  asm volatile("s_waitcnt vmcnt(4)" ::: "memory");   // t0 complete; t1-kh0 in flight
  GBAR();

  for (int j = 0; j < (NT >> 1); ++j) {
    const int tY  = 2 * j + 1;                      // Y kh1 staged ph0/ph1 (always valid)
    const int tX2 = min(2 * j + 2, NT - 1);         // clamped: tail stages land in freed
    const int tY2 = min(2 * j + 3, NT - 1);         // slots and are never read
    // ph0: X kk0, ni01
    RD_A(0, 0) RD_B(0, 0, 0)
    G_STAGE(gA, 1, 0, 1, tY)
    GBAR(); MMQ(0) GBAR();
    // ph1: X kk0, ni23
    RD_B(0, 0, 2)
    G_STAGE(gB, 1, 32768, 1, tY)
    GBAR(); MMQ(2) GBAR();
    // ph2: X kk1, ni01
    RD_A(0, 1) RD_B(0, 1, 0)
    G_STAGE(gA, 0, 0, 0, tX2)
    GBAR(); MMQ(0) GBAR();
    // ph3: X kk1, ni23  (+ counted vmcnt: Y-tile fully staged after barrier)
    RD_B(0, 1, 2)
    G_STAGE(gB, 0, 32768, 0, tX2)
    asm volatile("s_waitcnt vmcnt(4)" ::: "memory");
    GBAR(); MMQ(2) GBAR();
    // ph4: Y kk0, ni01
    RD_A(1, 0) RD_B(1, 0, 0)
    G_STAGE(gA, 0, 0, 1, tX2)
    GBAR(); MMQ(0) GBAR();
    // ph5: Y kk0, ni23
    RD_B(1, 0, 2)
    G_STAGE(gB, 0, 32768, 1, tX2)
    GBAR(); MMQ(2) GBAR();
    // ph6: Y kk1, ni01
    RD_A(1, 1) RD_B(1, 1, 0)
    G_STAGE(gA, 1, 0, 0, tY2)
    GBAR(); MMQ(0) GBAR();
    // ph7: Y kk1, ni23  (+ counted vmcnt: next X-tile staged after barrier)
    RD_B(1, 1, 2)
    G_STAGE(gB, 1, 32768, 0, tY2)
    asm volatile("s_waitcnt vmcnt(4)" ::: "memory");
    GBAR(); MMQ(2) GBAR();
  }

  // epilogue: acc -> C (row = M-side (lane>>4)*4 + r, col = N-side lane&15)
#pragma unroll
  for (int mi = 0; mi < 8; ++mi)
#pragma unroll
    for (int ni = 0; ni < 4; ++ni) {
      size_t base = (size_t)(bm0 + wm * 128 + mi * 16 + qw * 4) * N +
                    bn0 + wn * 64 + ni * 16 + lr;
#pragma unroll
      for (int r = 0; r < 4; ++r) {
        float v = acc[mi][ni][r];
        if constexpr (sizeof(OutT) == 2) C[base + (size_t)r * N] = f2bf(v);
        else                             C[base + (size_t)r * N] = v;
      }
    }
}

// ---------------- rope_pack: RoPE q + RoPE k (pre-scaled) + V pack, fused --------
__global__ void rope_pack_kernel(const u16* __restrict__ qkv, const int* __restrict__ pid,
                                 u16* __restrict__ qb, u16* __restrict__ kb,
                                 u16* __restrict__ vT) {
  __shared__ u16 tile[64][72];
  const int bid = blockIdx.x, tid = threadIdx.x;
  if (bid < 16384) {
    int idx = bid * 256 + tid;
    int i = idx & 31;
    int s = (idx >> 5) & (Sseq - 1);
    int h = (idx >> 16) & (NH - 1);
    int b = idx >> 21;
    int row = b * Sseq + s;
    const u16* src = qkv + (size_t)row * NQKV + h * HD + i;
    float q0 = bf2f(src[0]);
    float q1 = bf2f(src[32]);
    float pos = (float)pid[row];
    float ang = pos * expf(-(float)i * (9.210340371976184f / 32.f));
    float c = cosf(ang), sn = sinf(ang);
    u16* dst = qb + ((size_t)(b * NH + h) * Sseq + s) * HD + i;
    dst[0]  = f2bf(q0 * c - q1 * sn);
    dst[32] = f2bf(q1 * c + q0 * sn);
  } else if (bid < 20480) {
    const float SCK = 0.18033688011112042f;  // log2(e)/8 folded into K
    int idx = (bid - 16384) * 256 + tid;
    int i = idx & 31;
    int s = (idx >> 5) & (Sseq - 1);
    int h = (idx >> 16) & (NKV - 1);
    int b = idx >> 19;
    int row = b * Sseq + s;
    const u16* src = qkv + (size_t)row * NQKV + 2048 + h * HD + i;
    float q0 = bf2f(src[0]);
    float q1 = bf2f(src[32]);
    float pos = (float)pid[row];
    float ang = pos * expf(-(float)i * (9.210340371976184f / 32.f));
    float c = cosf(ang), sn = sinf(ang);
    u16* dst = kb + ((size_t)(b * NKV + h) * Sseq + s) * HD + i;
    dst[0]  = f2bf((q0 * c - q1 * sn) * SCK);
    dst[32] = f2bf((q1 * c + q0 * sn) * SCK);
  } else {
    int pidx = bid - 20480;                  // [0,512)
    int s0 = (pidx & 31) * 64;
    int bh = pidx >> 5;
    int b = bh >> 3, hkv = bh & 7;
#pragma unroll
    for (int ii = 0; ii < 16; ++ii) {
      int lin = ii * 256 + tid;
      int sl = lin >> 6, d = lin & 63;
      tile[sl][d] = qkv[(size_t)(b * Sseq + s0 + sl) * NQKV + 2560 + hkv * HD + d];
    }
    __syncthreads();
#pragma unroll
    for (int ii = 0; ii < 16; ++ii) {
      int lin = ii * 256 + tid;
      int d = lin >> 6, sl = lin & 63;
      vT[((size_t)(bh * 32 + (s0 >> 6)) * HD + d) * 64 + sl] = tile[sl][d];
    }
  }
}

// ---------------- attn: LDS-staged K/V (round-11-proven) ----------
__device__ __forceinline__ void stage_kv(const char* gK, const char* gV,
                                         char* lK, char* lV, int wid, int lane) {
#pragma unroll
  for (int i = 0; i < 2; ++i) {
    int base = wid * 1024 + i * 4096;
    int lo = base + lane * 16;
    int so = lo ^ (((lo >> 7) & 7) << 4);
    GLD_LDS16(gK + so, lK + base);
    GLD_LDS16(gV + so, lV + base);
  }
}

template <bool MASKED>
__device__ __forceinline__ void attn_step(int k0, int qg, int hi, int q,
                                          const char* __restrict__ lK,
                                          const char* __restrict__ lV,
                                          const bf16x8 (&qf)[4],
                                          f32x16& o0, f32x16& o1,
                                          float& m, float& lsum) {
  bf16x8 kf0[4], kf1[4];
#pragma unroll
  for (int dk = 0; dk < 4; ++dk) {
    int a = (q << 7) | (((dk << 5) | (hi << 4)) ^ ((q & 7) << 4));
    kf0[dk] = *(const bf16x8*)(lK + a);
    kf1[dk] = *(const bf16x8*)(lK + a + 4096);
  }
  f32x16 st0 = {}, st1 = {};
  __builtin_amdgcn_s_setprio(1);
#pragma unroll
  for (int dk = 0; dk < 4; ++dk) {
    st0 = MFMA32(kf0[dk], qf[dk], st0);
    st1 = MFMA32(kf1[dk], qf[dk], st1);
  }
  __builtin_amdgcn_s_setprio(0);
  bf16x8 vf0[4], vf1[4];
#pragma unroll
  for (int ks = 0; ks < 4; ++ks) {
    int a = (q << 7) | (((ks << 5) | (hi << 4)) ^ ((q & 7) << 4));
    vf0[ks] = *(const bf16x8*)(lV + a);
    vf1[ks] = *(const bf16x8*)(lV + a + 4096);
  }
  if (MASKED) {
#pragma unroll
    for (int r = 0; r < 16; ++r) {
      const int koff = (r & 3) + 8 * (r >> 2) + 4 * hi;
      if (k0 + koff > qg)      st0[r] = -3.0e38f;
      if (k0 + 32 + koff > qg) st1[r] = -3.0e38f;
    }
  }
  float t01[16];
#pragma unroll
  for (int r = 0; r < 16; ++r) t01[r] = fmaxf(st0[r], st1[r]);
#pragma unroll
  for (int s = 8; s > 0; s >>= 1)
#pragma unroll
    for (int r = 0; r < s; ++r) t01[r] = fmaxf(t01[r], t01[r + s]);
  float tmax = t01[0];
  if (__any(tmax > m + 8.f)) {                // defer-max (T13)
    float tx = fmaxf(tmax, __shfl_xor(tmax, 32));
    float mnew = fmaxf(m, tx);
    float al = exp2f(m - mnew);
    lsum *= al;
#pragma unroll
    for (int r = 0; r < 16; ++r) { o0[r] *= al; o1[r] *= al; }
    m = mnew;
  }
  float ps[16];
#pragma unroll
  for (int r = 0; r < 16; ++r) {
    float e0 = exp2f(st0[r] - m), e1 = exp2f(st1[r] - m);
    st0[r] = e0; st1[r] = e1;
    ps[r] = e0 + e1;
  }
#pragma unroll
  for (int s = 8; s > 0; s >>= 1)
#pragma unroll
    for (int r = 0; r < s; ++r) ps[r] += ps[r + s];
  lsum += ps[0];
  bf16x8 pa[4];
#pragma unroll
  for (int ks = 0; ks < 4; ++ks) {
    const int sel = (ks & 1) * 8;
    f32x16& stt = (ks < 2) ? st0 : st1;
    uint32_t X0, Y0, X1, Y1;
    asm("v_cvt_pk_bf16_f32 %0, %1, %2" : "=v"(X0) : "v"(stt[sel + 0]), "v"(stt[sel + 1]));
    asm("v_cvt_pk_bf16_f32 %0, %1, %2" : "=v"(Y0) : "v"(stt[sel + 4]), "v"(stt[sel + 5]));
    asm("v_cvt_pk_bf16_f32 %0, %1, %2" : "=v"(X1) : "v"(stt[sel + 2]), "v"(stt[sel + 3]));
    asm("v_cvt_pk_bf16_f32 %0, %1, %2" : "=v"(Y1) : "v"(stt[sel + 6]), "v"(stt[sel + 7]));
    asm volatile("v_permlane32_swap_b32 %0, %1" : "+v"(X0), "+v"(Y0));
    asm volatile("v_permlane32_swap_b32 %0, %1" : "+v"(X1), "+v"(Y1));
    union { uint32_t w[4]; bf16x8 v; } u_;
    u_.w[0] = X0; u_.w[1] = X1; u_.w[2] = Y0; u_.w[3] = Y1;
    pa[ks] = u_.v;
  }
  __builtin_amdgcn_s_setprio(1);
#pragma unroll
  for (int ks = 0; ks < 4; ++ks) {
    o0 = MFMA32(vf0[ks], pa[ks], o0);
    o1 = MFMA32(vf1[ks], pa[ks], o1);
  }
  __builtin_amdgcn_s_setprio(0);
}

__global__ __launch_bounds__(256) void attn_kernel(const u16* __restrict__ qb,
                                                   const u16* __restrict__ kb,
                                                   const u16* __restrict__ vT,
                                                   u16* __restrict__ aout) {
  __shared__ __align__(16) char smem[32768];
  const int tid = threadIdx.x;
  const int lane = tid & 63, wid = tid >> 6;
  const int q = lane & 31, hi = lane >> 5;
  const int g = blockIdx.x * 4 + wid;
  const int bh = g & 63;
  const int qt = 63 - (g >> 6);
  const int b = bh >> 5, h = bh & 31, hkv = h >> 2;
  const int qbase = qt * 32, qg = qbase + q;

  const u16* qp = qb + ((size_t)bh * Sseq + qg) * HD + hi * 8;
  bf16x8 qf[4];
#pragma unroll
  for (int dk = 0; dk < 4; ++dk) qf[dk] = *(const bf16x8*)(qp + dk * 16);

  const char* gK = (const char*)(kb + (size_t)(b * NKV + hkv) * Sseq * HD);
  const char* gV = (const char*)(vT + (size_t)(b * NKV + hkv) * Sseq * HD);

  f32x16 o0 = {}, o1 = {};
  float m = -INFINITY, lsum = 0.f;
  const int ntiles = (qt >> 1) + 1;

  stage_kv(gK, gV, smem, smem + 16384, wid, lane);
  __syncthreads();
  int cur = 0;
  for (int kt = 0; kt < ntiles - 1; ++kt) {
    int nxt = cur ^ 1;
    stage_kv(gK + (size_t)(kt + 1) * 8192, gV + (size_t)(kt + 1) * 8192,
             smem + nxt * 8192, smem + 16384 + nxt * 8192, wid, lane);
    attn_step<false>(kt * 64, qg, hi, q, smem + cur * 8192,
                     smem + 16384 + cur * 8192, qf, o0, o1, m, lsum);
    __syncthreads();
    cur = nxt;
  }
  attn_step<true>((ntiles - 1) * 64, qg, hi, q, smem + cur * 8192,
                  smem + 16384 + cur * 8192, qf, o0, o1, m, lsum);
  __syncthreads();

  lsum += __shfl_xor(lsum, 32);
  const float inv = 1.f / lsum;

  uint32_t* lw = (uint32_t*)smem + wid * (32 * 33);
#pragma unroll
  for (int rr = 0; rr < 16; rr += 2) {
    const int d2 = ((rr >> 1) & 1) + 4 * (rr >> 2) + 2 * hi;
    uint32_t w0, w1;
    asm("v_cvt_pk_bf16_f32 %0, %1, %2" : "=v"(w0) : "v"(o0[rr] * inv), "v"(o0[rr + 1] * inv));
    asm("v_cvt_pk_bf16_f32 %0, %1, %2" : "=v"(w1) : "v"(o1[rr] * inv), "v"(o1[rr + 1] * inv));
    lw[d2 * 33 + q]        = w0;
    lw[(16 + d2) * 33 + q] = w1;
  }
  asm volatile("s_waitcnt lgkmcnt(0)" ::: "memory");
  __builtin_amdgcn_sched_barrier(0);
  uint32_t wv[16];
#pragma unroll
  for (int jj = 0; jj < 16; ++jj) wv[jj] = lw[(hi * 16 + jj) * 33 + q];
  uint4* op4 = (uint4*)(aout + (size_t)(b * Sseq + qbase + q) * (NH * HD) + h * HD + hi * 32);
#pragma unroll
  for (int k4 = 0; k4 < 4; ++k4)
    op4[k4] = make_uint4(wv[4 * k4], wv[4 * k4 + 1], wv[4 * k4 + 2], wv[4 * k4 + 3]);
}

extern "C" void kernel_launch(void* const* d_in, const int* in_sizes, int n_in,
                              void* d_out, int out_size, void* d_ws, size_t ws_size,
                              hipStream_t stream) {
  const float* x  = (const float*)d_in[0];
  const int*   pid= (const int*)d_in[1];
  const float* Wq = (const float*)d_in[2];
  const float* Wk = (const float*)d_in[3];
  const float* Wv = (const float*)d_in[4];
  const float* Wo = (const float*)d_in[5];
  const float* Aq = (const float*)d_in[6];
  const float* Bq = (const float*)d_in[7];
  const float* Ak = (const float*)d_in[8];
  const float* Bk = (const float*)d_in[9];
  const float* Av = (const float*)d_in[10];
  const float* Bv = (const float*)d_in[11];
  const float* Ao = (const float*)d_in[12];
  const float* Bo = (const float*)d_in[13];
  float* out = (float*)d_out;

  char* w = (char*)d_ws;
  u16*   x_bf    = (u16*)w;   w += (size_t)Mrows * Hdim * 2;
  u16*   weffqkv = (u16*)w;   w += (size_t)NQKV * Hdim * 2;
  u16*   weffo   = (u16*)w;   w += (size_t)Hdim * Hdim * 2;
  u16*   qkv     = (u16*)w;   w += (size_t)Mrows * NQKV * 2;
  u16*   qbb     = (u16*)w;   w += (size_t)Bsz * NH * Sseq * HD * 2;
  u16*   kbb     = (u16*)w;   w += (size_t)Bsz * NKV * Sseq * HD * 2;
  u16*   vTb     = (u16*)w;   w += (size_t)Bsz * NKV * Sseq * HD * 2;
  u16*   aoutb   = (u16*)w;   w += (size_t)Mrows * (NH * HD) * 2;

  prep_kernel<<<49152, 256, 0, stream>>>(x, x_bf,
                                         Wq, Aq, Bq, Wk, Ak, Bk, Wv, Av, Bv, Wo, Ao, Bo,
                                         weffqkv, weffo);

  gemm256<u16><<<dim3(16, 12), 512, 0, stream>>>(x_bf, weffqkv, qkv, Mrows, NQKV, Hdim);

  rope_pack_kernel<<<20992, 256, 0, stream>>>(qkv, pid, qbb, kbb, vTb);

  attn_kernel<<<1024, 256, 0, stream>>>(qbb, kbb, vTb, aoutb);

  gemm256<float><<<dim3(16, 8), 512, 0, stream>>>(aoutb, weffo, out, Mrows, 2048, 2048);
}